// Round 2
// baseline (1763.564 us; speedup 1.0000x reference)
//
#include <hip/hip_runtime.h>
#include <hip/hip_bf16.h>
#include <cmath>

#define DD 1536
#define FF 6144

typedef __bf16 bf16_t;
typedef __bf16 bf16x8 __attribute__((ext_vector_type(8)));
typedef __bf16 bf16x4 __attribute__((ext_vector_type(4)));
typedef float  f32x4  __attribute__((ext_vector_type(4)));

__device__ __forceinline__ void async_load16(const bf16_t* g, bf16_t* l) {
  __builtin_amdgcn_global_load_lds(
      (const __attribute__((address_space(1))) void*)g,
      (__attribute__((address_space(3))) void*)l, 16, 0, 0);
}

// ---------------- weight fp32 -> bf16 transpose ----------------
__global__ __launch_bounds__(256) void transpose_to_bf16(
    const float* __restrict__ W, bf16_t* __restrict__ Wt, int K, int N) {
  __shared__ float tile[32][33];
  const int tx = threadIdx.x, ty = threadIdx.y;         // 32 x 8
  const int n0 = blockIdx.x * 32, k0 = blockIdx.y * 32;
#pragma unroll
  for (int i = 0; i < 4; i++)
    tile[ty + 8 * i][tx] = W[(size_t)(k0 + ty + 8 * i) * N + n0 + tx];
  __syncthreads();
#pragma unroll
  for (int i = 0; i < 4; i++)
    Wt[(size_t)(n0 + ty + 8 * i) * K + k0 + tx] = (bf16_t)tile[tx][ty + 8 * i];
}

// ---------------- plain fp32 -> bf16 cast ----------------
__global__ __launch_bounds__(256) void cast_bf16(
    const float* __restrict__ x, bf16_t* __restrict__ o, int n4) {
  const int stride = gridDim.x * 256;
  for (int i = blockIdx.x * 256 + threadIdx.x; i < n4; i += stride) {
    f32x4 v = ((const f32x4*)x)[i];
    bf16x4 r;
#pragma unroll
    for (int e = 0; e < 4; e++) r[e] = (bf16_t)v[e];
    ((bf16x4*)o)[i] = r;
  }
}

// ---------------- block reduction helper ----------------
__device__ __forceinline__ void breduce2(float& a, float& b) {
#pragma unroll
  for (int off = 32; off; off >>= 1) {
    a += __shfl_xor(a, off);
    b += __shfl_xor(b, off);
  }
  __shared__ float sa[4], sb[4];
  const int w = threadIdx.x >> 6, ln = threadIdx.x & 63;
  if (ln == 0) { sa[w] = a; sb[w] = b; }
  __syncthreads();
  a = (sa[0] + sa[1]) + (sa[2] + sa[3]);
  b = (sb[0] + sb[1]) + (sb[2] + sb[3]);
  __syncthreads();
}

// ---------------- one norm over x rows: RMS (w) or LN (w,b) -> bf16 ----------------
enum { NM_RMS = 0, NM_LN = 1 };
template <int MODE>
__global__ __launch_bounds__(256) void norm_one(
    const float* __restrict__ x, const float* __restrict__ w,
    const float* __restrict__ bb, bf16_t* __restrict__ o) {
  const int row = blockIdx.x, t = threadIdx.x;
  const float* xr = x + (size_t)row * DD;
  f32x4 v0 = ((const f32x4*)xr)[t];
  f32x4 v1 = 0.0f;
  if (t < 128) v1 = ((const f32x4*)xr)[256 + t];
  float s = 0.f, s2 = 0.f;
#pragma unroll
  for (int e = 0; e < 4; e++) { s += v0[e]; s2 += v0[e] * v0[e]; }
  if (t < 128) {
#pragma unroll
    for (int e = 0; e < 4; e++) { s += v1[e]; s2 += v1[e] * v1[e]; }
  }
  breduce2(s, s2);
  const float mu = s * (1.f / DD), ms = s2 * (1.f / DD);
  const float rq = rsqrtf(ms + 1e-7f);
  const float rln = rsqrtf(ms - mu * mu + 1e-5f);

  auto emit = [&](int ci, f32x4 v) {
    const int i0 = ci * 4;
    bf16x4 ov;
#pragma unroll
    for (int e = 0; e < 4; e++) {
      const float f = v[e];
      const int ix = i0 + e;
      if constexpr (MODE == NM_RMS) ov[e] = (bf16_t)(f * rq * w[ix]);
      else                          ov[e] = (bf16_t)((f - mu) * rln * w[ix] + bb[ix]);
    }
    *(bf16x4*)(o + (size_t)row * DD + i0) = ov;
  };
  emit(t, v0);
  if (t < 128) emit(256 + t, v1);
}

// ---------------- norms over text: raw bf16 + rms(ck) ----------------
__global__ __launch_bounds__(256) void norm_t_kernel(
    const float* __restrict__ te, const float* __restrict__ ckw,
    bf16_t* __restrict__ tb, bf16_t* __restrict__ tck) {
  const int row = blockIdx.x, t = threadIdx.x;
  const float* xr = te + (size_t)row * DD;
  f32x4 v0 = ((const f32x4*)xr)[t];
  f32x4 v1 = 0.0f;
  if (t < 128) v1 = ((const f32x4*)xr)[256 + t];
  float s = 0.f, s2 = 0.f;
#pragma unroll
  for (int e = 0; e < 4; e++) { s2 += v0[e] * v0[e]; }
  if (t < 128) {
#pragma unroll
    for (int e = 0; e < 4; e++) { s2 += v1[e] * v1[e]; }
  }
  breduce2(s, s2);
  const float rq = rsqrtf(s2 * (1.f / DD) + 1e-7f);
  auto emit = [&](int ci, f32x4 v) {
    const int i0 = ci * 4;
    bf16x4 ob, oc;
#pragma unroll
    for (int e = 0; e < 4; e++) {
      const float f = v[e];
      ob[e] = (bf16_t)f;
      oc[e] = (bf16_t)(f * rq * ckw[i0 + e]);
    }
    const size_t o = (size_t)row * DD + i0;
    *(bf16x4*)(tb + o) = ob;
    *(bf16x4*)(tck + o) = oc;
  };
  emit(t, v0);
  if (t < 128) emit(256 + t, v1);
}

// ---------------- row softmax (fp32 in, bf16 out IN PLACE over same rows) ----------
template <int NC>
__global__ __launch_bounds__(256) void softmax_rows(float* __restrict__ S) {
  constexpr int NV = (NC / 4 + 255) / 256;
  const int t = threadIdx.x;
  const size_t row = blockIdx.x;
  float* sr = S + row * NC;
  f32x4 v[NV];
  float mx = -3.4e38f;
#pragma unroll
  for (int i = 0; i < NV; i++) {
    const int idx = t + i * 256;
    if (idx < NC / 4) {
      v[i] = ((const f32x4*)sr)[idx];
#pragma unroll
      for (int e = 0; e < 4; e++) mx = fmaxf(mx, v[i][e]);
    }
  }
#pragma unroll
  for (int off = 32; off; off >>= 1) mx = fmaxf(mx, __shfl_xor(mx, off));
  __shared__ float sm[4];
  const int w = t >> 6, ln = t & 63;
  if (ln == 0) sm[w] = mx;
  __syncthreads();
  mx = fmaxf(fmaxf(sm[0], sm[1]), fmaxf(sm[2], sm[3]));
  __syncthreads();
  float sum = 0.f;
#pragma unroll
  for (int i = 0; i < NV; i++) {
    const int idx = t + i * 256;
    if (idx < NC / 4) {
#pragma unroll
      for (int e = 0; e < 4; e++) {
        const float ev = __expf(v[i][e] - mx);
        v[i][e] = ev;
        sum += ev;
      }
    }
  }
#pragma unroll
  for (int off = 32; off; off >>= 1) sum += __shfl_xor(sum, off);
  __shared__ float ss[4];
  if (ln == 0) ss[w] = sum;
  __syncthreads();
  sum = (ss[0] + ss[1]) + (ss[2] + ss[3]);
  const float inv = 1.f / sum;
  bf16_t* pr = (bf16_t*)S + row * NC * 2;  // bf16 row in first half of fp32 row bytes
#pragma unroll
  for (int i = 0; i < NV; i++) {
    const int idx = t + i * 256;
    if (idx < NC / 4) {
      bf16x4 o;
#pragma unroll
      for (int e = 0; e < 4; e++) o[e] = (bf16_t)(v[i][e] * inv);
      *(bf16x4*)(pr + idx * 4) = o;
    }
  }
}

// ---------------- GEMM: C(MxN) = A(MxK) * B^T  (B stored N x K), both bf16 ----------------
// 128x128 tile, BK=32, 4 waves each 64x64, mfma 16x16x32 bf16, global_load_lds staging.
enum { EPI_BF16 = 0, EPI_F32_SCALE = 1, EPI_ADD_X = 2, EPI_ACC = 3, EPI_GELU = 4, EPI_TRANS = 5 };

template <int EPI>
__global__ __launch_bounds__(256) void gemm_bt(
    const bf16_t* __restrict__ A, const bf16_t* __restrict__ B,
    const float* __restrict__ bias, void* __restrict__ Cout,
    const float* __restrict__ Xres,
    int nK, int lda, int ldb, int ldc,
    float scale, int t_ld, int t_bshift, size_t t_bstride) {
  __shared__ __align__(16) bf16_t As[2][128 * 32];
  __shared__ __align__(16) bf16_t Bs[2][128 * 32];
  const int tid = threadIdx.x;
  const int m0 = blockIdx.y * 128, n0 = blockIdx.x * 128;
  const int wave = tid >> 6, lane = tid & 63, l15 = lane & 15, hi = lane >> 4;
  const int wm = wave >> 1, wn = wave & 1;
  const int srow = tid >> 2, scol = (tid & 3) << 3;

  const bf16_t* ga = A + (size_t)(m0 + srow) * lda + scol;
  const bf16_t* gb = B + (size_t)(n0 + srow) * ldb + scol;
  const int lo = wave * 512;  // wave-uniform LDS element offset

  f32x4 acc[4][4];
#pragma unroll
  for (int i = 0; i < 4; i++)
#pragma unroll
    for (int j = 0; j < 4; j++) acc[i][j] = 0.0f;

  auto stage = [&](int buf, int kt) {
    const bf16_t* a = ga + (size_t)kt * 32;
    const bf16_t* b = gb + (size_t)kt * 32;
    async_load16(a, &As[buf][lo]);
    async_load16(a + (size_t)64 * lda, &As[buf][2048 + lo]);
    async_load16(b, &Bs[buf][lo]);
    async_load16(b + (size_t)64 * ldb, &Bs[buf][2048 + lo]);
  };

  auto compute = [&](int buf) {
    bf16x8 af[4], bg[4];
#pragma unroll
    for (int i = 0; i < 4; i++)
      af[i] = *(const bf16x8*)&As[buf][(wm * 64 + i * 16 + l15) * 32 + hi * 8];
#pragma unroll
    for (int j = 0; j < 4; j++)
      bg[j] = *(const bf16x8*)&Bs[buf][(wn * 64 + j * 16 + l15) * 32 + hi * 8];
#pragma unroll
    for (int i = 0; i < 4; i++)
#pragma unroll
      for (int j = 0; j < 4; j++)
        acc[i][j] = __builtin_amdgcn_mfma_f32_16x16x32_bf16(af[i], bg[j], acc[i][j], 0, 0, 0);
  };

  stage(0, 0);
  __syncthreads();
  for (int kt = 0; kt < nK; ++kt) {
    if (kt + 1 < nK) stage((kt + 1) & 1, kt + 1);
    compute(kt & 1);
    __syncthreads();
  }

  // epilogue: C/D frag mapping col=lane&15, row=(lane>>4)*4+reg
#pragma unroll
  for (int i = 0; i < 4; i++) {
    const int r0 = m0 + wm * 64 + i * 16 + hi * 4;
#pragma unroll
    for (int j = 0; j < 4; j++) {
      const int c = n0 + wn * 64 + j * 16 + l15;
      const float bv = (bias != nullptr) ? bias[c] : 0.f;
      f32x4 v = acc[i][j];
      if constexpr (EPI == EPI_BF16) {
        bf16_t* C = (bf16_t*)Cout;
#pragma unroll
        for (int r = 0; r < 4; r++) C[(size_t)(r0 + r) * ldc + c] = (bf16_t)(v[r] + bv);
      } else if constexpr (EPI == EPI_F32_SCALE) {
        float* C = (float*)Cout;
#pragma unroll
        for (int r = 0; r < 4; r++) C[(size_t)(r0 + r) * ldc + c] = v[r] * scale;
      } else if constexpr (EPI == EPI_ADD_X) {
        float* C = (float*)Cout;
#pragma unroll
        for (int r = 0; r < 4; r++) {
          const size_t ix = (size_t)(r0 + r) * ldc + c;
          C[ix] = Xres[ix] + v[r] + bv;
        }
      } else if constexpr (EPI == EPI_ACC) {
        float* C = (float*)Cout;
#pragma unroll
        for (int r = 0; r < 4; r++) {
          const size_t ix = (size_t)(r0 + r) * ldc + c;
          C[ix] += v[r] + bv;
        }
      } else if constexpr (EPI == EPI_GELU) {
        bf16_t* C = (bf16_t*)Cout;
#pragma unroll
        for (int r = 0; r < 4; r++) {
          const float h = v[r] + bv;
          const float g = 0.5f * h * (1.f + erff(h * 0.70710678118654752f));
          C[(size_t)(r0 + r) * ldc + c] = (bf16_t)g;
        }
      } else {  // EPI_TRANS: write C^T batched: out[b][c][n]
        const int b = r0 >> t_bshift;
        const int n = r0 & ((1 << t_bshift) - 1);
        bf16_t* C = (bf16_t*)Cout + (size_t)b * t_bstride + (size_t)c * t_ld + n;
        bf16x4 o;
#pragma unroll
        for (int r = 0; r < 4; r++) o[r] = (bf16_t)(v[r] + bv);
        *(bf16x4*)C = o;
      }
    }
  }
}

// ---------------- host ----------------
extern "C" void kernel_launch(void* const* d_in, const int* in_sizes, int n_in,
                              void* d_out, int out_size, void* d_ws, size_t ws_size,
                              hipStream_t stream) {
  (void)in_sizes; (void)n_in; (void)out_size; (void)ws_size;
  const float* x   = (const float*)d_in[0];
  const float* te  = (const float*)d_in[1];
  const float* sqw = (const float*)d_in[2];
  const float* skw = (const float*)d_in[3];
  const float* cqw = (const float*)d_in[4];
  const float* ckw = (const float*)d_in[5];
  const float* lnw = (const float*)d_in[6];
  const float* lnb = (const float*)d_in[7];
  const float* Wq = (const float*)d_in[8];  const float* bq = (const float*)d_in[9];
  const float* Wk = (const float*)d_in[10]; const float* bk = (const float*)d_in[11];
  const float* Wv = (const float*)d_in[12]; const float* bv = (const float*)d_in[13];
  const float* Wo = (const float*)d_in[14]; const float* bo = (const float*)d_in[15];
  const float* CWq = (const float*)d_in[16]; const float* Cbq = (const float*)d_in[17];
  const float* CWk = (const float*)d_in[18]; const float* Cbk = (const float*)d_in[19];
  const float* CWv = (const float*)d_in[20]; const float* Cbv = (const float*)d_in[21];
  const float* CWo = (const float*)d_in[22]; const float* Cbo = (const float*)d_in[23];
  const float* W1 = (const float*)d_in[24]; const float* b1 = (const float*)d_in[25];
  const float* W2 = (const float*)d_in[26]; const float* b2 = (const float*)d_in[27];
  float* out = (float*)d_out;

  // ---- workspace layout: peak ~178 MB ----
  bf16_t* p = (bf16_t*)d_ws;
  bf16_t* WT0 = p; p += (size_t)DD * FF;     // 18.9 MB  weight slot A
  bf16_t* WT1 = p; p += (size_t)DD * FF;     // 18.9 MB  weight slot B
  bf16_t* N0  = p; p += (size_t)8192 * DD;   // 25.2 MB  norm out / attn-pre (aliased lifetimes)
  bf16_t* Qb  = p; p += (size_t)8192 * DD;   // 25.2 MB  Q   (later CQ)
  bf16_t* Kb  = p; p += (size_t)8192 * DD;   // 25.2 MB  K   (later CK: 1024 rows)
  bf16_t* Vt  = p; p += (size_t)8192 * DD;   // 25.2 MB  V^T (later CV^T)
  bf16_t* Tb  = p; p += (size_t)1024 * DD;   // 3.15 MB  text raw bf16
  bf16_t* Tck = p; p += (size_t)1024 * DD;   // 3.15 MB  text rms(ck)
  float*  S   = (float*)p;                   // 33.55 MB: 2048x4096 f32 score chunk /
                                             //   cross scores 2x4096x512 f32 / FFN gelu chunk bf16

  const dim3 blk(256);
  const dim3 tb(32, 8);
  auto g2 = [](int M, int N) { return dim3(N / 128, M / 128); };
  const float scl = 0.025515518153991442f;  // 1/sqrt(1536)

  auto T = [&](const float* W, bf16_t* Wt, int K, int N) {
    transpose_to_bf16<<<dim3(N / 32, K / 32), tb, 0, stream>>>(W, Wt, K, N);
  };

  // ---- V projection (raw x) ----
  T(Wv, WT0, DD, DD);
  cast_bf16<<<2048, blk, 0, stream>>>(x, N0, 8192 * DD / 4);
  gemm_bt<EPI_TRANS><<<g2(8192, DD), blk, 0, stream>>>(N0, WT0, bv, Vt, nullptr, 48, DD, DD, 0, 1.f, 4096, 12, (size_t)DD * 4096);
  // ---- Q projection ----
  T(Wq, WT1, DD, DD);
  norm_one<NM_RMS><<<8192, blk, 0, stream>>>(x, sqw, nullptr, N0);
  gemm_bt<EPI_BF16><<<g2(8192, DD), blk, 0, stream>>>(N0, WT1, bq, Qb, nullptr, 48, DD, DD, DD, 1.f, 0, 0, 0);
  // ---- K projection ----
  T(Wk, WT0, DD, DD);
  norm_one<NM_RMS><<<8192, blk, 0, stream>>>(x, skw, nullptr, N0);
  gemm_bt<EPI_BF16><<<g2(8192, DD), blk, 0, stream>>>(N0, WT0, bk, Kb, nullptr, 48, DD, DD, DD, 1.f, 0, 0, 0);

  // ---- self-attention: per batch, per 2048-row chunk (S reused) ----
  for (int b = 0; b < 2; b++) {
    for (int mc = 0; mc < 2; mc++) {
      const size_t rowoff = (size_t)b * 4096 + mc * 2048;
      gemm_bt<EPI_F32_SCALE><<<g2(2048, 4096), blk, 0, stream>>>(
          Qb + rowoff * DD, Kb + (size_t)b * 4096 * DD, nullptr,
          S, nullptr, 48, DD, DD, 4096, scl, 0, 0, 0);
      softmax_rows<4096><<<2048, blk, 0, stream>>>(S);
      gemm_bt<EPI_BF16><<<g2(2048, DD), blk, 0, stream>>>(
          (bf16_t*)S, Vt + (size_t)b * DD * 4096, nullptr,
          N0 + rowoff * DD, nullptr, 128, 8192, 4096, DD, 1.f, 0, 0, 0);
    }
  }
  // ---- out = x + attn_pre * Wo^T + bo ----
  T(Wo, WT1, DD, DD);
  gemm_bt<EPI_ADD_X><<<g2(8192, DD), blk, 0, stream>>>(N0, WT1, bo, out, x, 48, DD, DD, DD, 1.f, 0, 0, 0);

  // ---- cross-attention ----
  T(CWq, WT0, DD, DD);
  norm_one<NM_RMS><<<8192, blk, 0, stream>>>(x, cqw, nullptr, N0);
  gemm_bt<EPI_BF16><<<g2(8192, DD), blk, 0, stream>>>(N0, WT0, Cbq, Qb, nullptr, 48, DD, DD, DD, 1.f, 0, 0, 0);
  norm_t_kernel<<<1024, blk, 0, stream>>>(te, ckw, Tb, Tck);
  T(CWk, WT1, DD, DD);
  gemm_bt<EPI_BF16><<<g2(1024, DD), blk, 0, stream>>>(Tck, WT1, Cbk, Kb, nullptr, 48, DD, DD, DD, 1.f, 0, 0, 0);
  T(CWv, WT0, DD, DD);
  gemm_bt<EPI_TRANS><<<g2(1024, DD), blk, 0, stream>>>(Tb, WT0, Cbv, Vt, nullptr, 48, DD, DD, 0, 1.f, 512, 9, (size_t)DD * 512);
  for (int b = 0; b < 2; b++) {
    gemm_bt<EPI_F32_SCALE><<<g2(4096, 512), blk, 0, stream>>>(
        Qb + (size_t)b * 4096 * DD, Kb + (size_t)b * 512 * DD, nullptr,
        S + (size_t)b * 4096 * 512, nullptr, 48, DD, DD, 512, scl, 0, 0, 0);
  }
  softmax_rows<512><<<8192, blk, 0, stream>>>(S);
  for (int b = 0; b < 2; b++) {
    gemm_bt<EPI_BF16><<<g2(4096, DD), blk, 0, stream>>>(
        (bf16_t*)S + (size_t)b * 4096 * 1024, Vt + (size_t)b * DD * 512, nullptr,
        N0 + (size_t)b * 4096 * DD, nullptr, 16, 1024, 512, DD, 1.f, 0, 0, 0);
  }
  T(CWo, WT1, DD, DD);
  gemm_bt<EPI_ACC><<<g2(8192, DD), blk, 0, stream>>>(N0, WT1, Cbo, out, nullptr, 48, DD, DD, DD, 1.f, 0, 0, 0);

  // ---- FFN in 4 column chunks of 1536 (S reused as bf16 gelu buffer) ----
  norm_one<NM_LN><<<8192, blk, 0, stream>>>(x, lnw, lnb, N0);
  T(W1, WT0, DD, FF);   // WT0 = W1^T (FF x DD)
  T(W2, WT1, FF, DD);   // WT1 = W2^T (DD x FF)
  bf16_t* Hc = (bf16_t*)S;  // 8192 x 1536 bf16 chunk
  for (int c = 0; c < 4; c++) {
    gemm_bt<EPI_GELU><<<g2(8192, DD), blk, 0, stream>>>(
        N0, WT0 + (size_t)c * DD * DD, b1 + c * DD, Hc, nullptr, 48, DD, DD, DD, 1.f, 0, 0, 0);
    gemm_bt<EPI_ACC><<<g2(8192, DD), blk, 0, stream>>>(
        Hc, WT1 + (size_t)c * DD, (c == 0) ? b2 : nullptr, out, nullptr, 48, DD, FF, DD, 1.f, 0, 0, 0);
  }
}

// Round 4
// 1556.178 us; speedup vs baseline: 1.1333x; 1.1333x over previous
//
#include <hip/hip_runtime.h>
#include <hip/hip_bf16.h>
#include <cmath>

#define DD 1536
#define FF 6144

typedef __bf16 bf16_t;
typedef __bf16 bf16x8 __attribute__((ext_vector_type(8)));
typedef __bf16 bf16x4 __attribute__((ext_vector_type(4)));
typedef float  f32x4  __attribute__((ext_vector_type(4)));

#define VM2 asm volatile("s_waitcnt vmcnt(2)" ::: "memory")
#define VM0 asm volatile("s_waitcnt vmcnt(0)" ::: "memory")
#define BAR __builtin_amdgcn_s_barrier()

__device__ __forceinline__ void async_load16(const bf16_t* g, bf16_t* l) {
  __builtin_amdgcn_global_load_lds(
      (const __attribute__((address_space(1))) void*)g,
      (__attribute__((address_space(3))) void*)l, 16, 0, 0);
}

// bijective XCD-aware remap (m204)
__device__ __forceinline__ void xcd_remap(int& bx, int& by) {
  const int gx = gridDim.x, gy = gridDim.y;
  int wg = by * gx + bx;
  const int nwg = gx * gy;
  const int q = nwg >> 3, r = nwg & 7, xcd = wg & 7, o = wg >> 3;
  wg = (xcd < r ? xcd * (q + 1) : r * (q + 1) + (xcd - r) * q) + o;
  bx = wg % gx;
  by = wg / gx;
}

// ---------------- weight fp32 -> bf16 transpose, optional per-K row scale ----------------
__global__ __launch_bounds__(256) void transpose_to_bf16(
    const float* __restrict__ W, bf16_t* __restrict__ Wt, int K, int N,
    const float* __restrict__ s) {
  __shared__ float tile[32][33];
  const int tx = threadIdx.x, ty = threadIdx.y;  // 32 x 8
  const int n0 = blockIdx.x * 32, k0 = blockIdx.y * 32;
#pragma unroll
  for (int i = 0; i < 4; i++)
    tile[ty + 8 * i][tx] = W[(size_t)(k0 + ty + 8 * i) * N + n0 + tx];
  __syncthreads();
  const float sc = (s != nullptr) ? s[k0 + tx] : 1.f;
#pragma unroll
  for (int i = 0; i < 4; i++)
    Wt[(size_t)(n0 + ty + 8 * i) * K + k0 + tx] = (bf16_t)(tile[tx][ty + 8 * i] * sc);
}

// ---------------- reduction helpers ----------------
__device__ __forceinline__ void breduce1(float& a) {
#pragma unroll
  for (int off = 32; off; off >>= 1) a += __shfl_xor(a, off);
  __shared__ float sa[4];
  const int w = threadIdx.x >> 6, ln = threadIdx.x & 63;
  if (ln == 0) sa[w] = a;
  __syncthreads();
  a = (sa[0] + sa[1]) + (sa[2] + sa[3]);
  __syncthreads();
}

__device__ __forceinline__ void breduce2(float& a, float& b) {
#pragma unroll
  for (int off = 32; off; off >>= 1) {
    a += __shfl_xor(a, off);
    b += __shfl_xor(b, off);
  }
  __shared__ float sa[4], sb[4];
  const int w = threadIdx.x >> 6, ln = threadIdx.x & 63;
  if (ln == 0) { sa[w] = a; sb[w] = b; }
  __syncthreads();
  a = (sa[0] + sa[1]) + (sa[2] + sa[3]);
  b = (sb[0] + sb[1]) + (sb[2] + sb[3]);
  __syncthreads();
}

// ---------------- x: shared rms factor -> xr = x*rq (bf16), xb = x (bf16) ----------------
__global__ __launch_bounds__(256) void norm_x2(
    const float* __restrict__ x, bf16_t* __restrict__ xr, bf16_t* __restrict__ xb) {
  const int row = blockIdx.x, t = threadIdx.x;
  const float* p = x + (size_t)row * DD;
  f32x4 v0 = ((const f32x4*)p)[t];
  f32x4 v1 = 0.0f;
  if (t < 128) v1 = ((const f32x4*)p)[256 + t];
  float s2 = 0.f;
#pragma unroll
  for (int e = 0; e < 4; e++) s2 += v0[e] * v0[e];
  if (t < 128) {
#pragma unroll
    for (int e = 0; e < 4; e++) s2 += v1[e] * v1[e];
  }
  breduce1(s2);
  const float rq = rsqrtf(s2 * (1.f / DD) + 1e-7f);
  auto emit = [&](int ci, f32x4 v) {
    bf16x4 orr, ob;
#pragma unroll
    for (int e = 0; e < 4; e++) {
      orr[e] = (bf16_t)(v[e] * rq);
      ob[e] = (bf16_t)v[e];
    }
    const size_t o = (size_t)row * DD + ci * 4;
    *(bf16x4*)(xr + o) = orr;
    *(bf16x4*)(xb + o) = ob;
  };
  emit(t, v0);
  if (t < 128) emit(256 + t, v1);
}

// ---------------- LayerNorm -> bf16 ----------------
__global__ __launch_bounds__(256) void norm_ln(
    const float* __restrict__ x, const float* __restrict__ w,
    const float* __restrict__ bb, bf16_t* __restrict__ o) {
  const int row = blockIdx.x, t = threadIdx.x;
  const float* p = x + (size_t)row * DD;
  f32x4 v0 = ((const f32x4*)p)[t];
  f32x4 v1 = 0.0f;
  if (t < 128) v1 = ((const f32x4*)p)[256 + t];
  float s = 0.f, s2 = 0.f;
#pragma unroll
  for (int e = 0; e < 4; e++) { s += v0[e]; s2 += v0[e] * v0[e]; }
  if (t < 128) {
#pragma unroll
    for (int e = 0; e < 4; e++) { s += v1[e]; s2 += v1[e] * v1[e]; }
  }
  breduce2(s, s2);
  const float mu = s * (1.f / DD);
  const float rln = rsqrtf(s2 * (1.f / DD) - mu * mu + 1e-5f);
  auto emit = [&](int ci, f32x4 v) {
    const int i0 = ci * 4;
    bf16x4 ov;
#pragma unroll
    for (int e = 0; e < 4; e++)
      ov[e] = (bf16_t)((v[e] - mu) * rln * w[i0 + e] + bb[i0 + e]);
    *(bf16x4*)(o + (size_t)row * DD + i0) = ov;
  };
  emit(t, v0);
  if (t < 128) emit(256 + t, v1);
}

// ---------------- text: Tb = raw bf16, Tck = text*rtq (ck_w folded into weight) ----------
__global__ __launch_bounds__(256) void norm_t2(
    const float* __restrict__ te, bf16_t* __restrict__ tb, bf16_t* __restrict__ tck) {
  const int row = blockIdx.x, t = threadIdx.x;
  const float* p = te + (size_t)row * DD;
  f32x4 v0 = ((const f32x4*)p)[t];
  f32x4 v1 = 0.0f;
  if (t < 128) v1 = ((const f32x4*)p)[256 + t];
  float s2 = 0.f;
#pragma unroll
  for (int e = 0; e < 4; e++) s2 += v0[e] * v0[e];
  if (t < 128) {
#pragma unroll
    for (int e = 0; e < 4; e++) s2 += v1[e] * v1[e];
  }
  breduce1(s2);
  const float rq = rsqrtf(s2 * (1.f / DD) + 1e-7f);
  auto emit = [&](int ci, f32x4 v) {
    bf16x4 ob, oc;
#pragma unroll
    for (int e = 0; e < 4; e++) {
      ob[e] = (bf16_t)v[e];
      oc[e] = (bf16_t)(v[e] * rq);
    }
    const size_t o = (size_t)row * DD + ci * 4;
    *(bf16x4*)(tb + o) = ob;
    *(bf16x4*)(tck + o) = oc;
  };
  emit(t, v0);
  if (t < 128) emit(256 + t, v1);
}

// ---------------- in-place bf16 row softmax ----------------
template <int NC>
__global__ __launch_bounds__(256) void softmax_bf16(bf16_t* __restrict__ S) {
  const int t = threadIdx.x;
  bf16_t* sr = S + (size_t)blockIdx.x * NC;
  constexpr int NV = (NC / 8 + 255) / 256;
  float v[NV][8];
  float mx = -3.4e38f;
#pragma unroll
  for (int i = 0; i < NV; i++) {
    const int idx = t + i * 256;
    if (idx * 8 < NC) {
      bf16x8 b = ((const bf16x8*)sr)[idx];
#pragma unroll
      for (int e = 0; e < 8; e++) {
        v[i][e] = (float)b[e];
        mx = fmaxf(mx, v[i][e]);
      }
    }
  }
#pragma unroll
  for (int off = 32; off; off >>= 1) mx = fmaxf(mx, __shfl_xor(mx, off));
  __shared__ float sm[4];
  const int w = t >> 6, ln = t & 63;
  if (ln == 0) sm[w] = mx;
  __syncthreads();
  mx = fmaxf(fmaxf(sm[0], sm[1]), fmaxf(sm[2], sm[3]));
  __syncthreads();
  float sum = 0.f;
#pragma unroll
  for (int i = 0; i < NV; i++) {
    const int idx = t + i * 256;
    if (idx * 8 < NC) {
#pragma unroll
      for (int e = 0; e < 8; e++) {
        v[i][e] = __expf(v[i][e] - mx);
        sum += v[i][e];
      }
    }
  }
#pragma unroll
  for (int off = 32; off; off >>= 1) sum += __shfl_xor(sum, off);
  __shared__ float ss[4];
  if (ln == 0) ss[w] = sum;
  __syncthreads();
  sum = (ss[0] + ss[1]) + (ss[2] + ss[3]);
  const float inv = 1.f / sum;
#pragma unroll
  for (int i = 0; i < NV; i++) {
    const int idx = t + i * 256;
    if (idx * 8 < NC) {
      bf16x8 o;
#pragma unroll
      for (int e = 0; e < 8; e++) o[e] = (bf16_t)(v[i][e] * inv);
      ((bf16x8*)sr)[idx] = o;
    }
  }
}

enum { EPI_BF16 = 0, EPI_F32_SCALE = 1, EPI_ADD_X = 2, EPI_ACC = 3, EPI_GELU = 4, EPI_TRANS = 5, EPI_BF16S = 6 };

// shared epilogue write for one 4-row fragment column
template <int EPI>
__device__ __forceinline__ void epi_frag(
    f32x4 v, int r0, int c, const float* bias, void* Cout, const float* Xres,
    int ldc, float scale, int t_ld, int t_bshift, size_t t_bstride) {
  const float bv = (bias != nullptr) ? bias[c] : 0.f;
  if constexpr (EPI == EPI_BF16) {
    bf16_t* C = (bf16_t*)Cout;
#pragma unroll
    for (int r = 0; r < 4; r++) C[(size_t)(r0 + r) * ldc + c] = (bf16_t)(v[r] + bv);
  } else if constexpr (EPI == EPI_F32_SCALE) {
    float* C = (float*)Cout;
#pragma unroll
    for (int r = 0; r < 4; r++) C[(size_t)(r0 + r) * ldc + c] = v[r] * scale;
  } else if constexpr (EPI == EPI_BF16S) {
    bf16_t* C = (bf16_t*)Cout;
#pragma unroll
    for (int r = 0; r < 4; r++) C[(size_t)(r0 + r) * ldc + c] = (bf16_t)(v[r] * scale);
  } else if constexpr (EPI == EPI_ADD_X) {
    float* C = (float*)Cout;
#pragma unroll
    for (int r = 0; r < 4; r++) {
      const size_t ix = (size_t)(r0 + r) * ldc + c;
      C[ix] = Xres[ix] + v[r] + bv;
    }
  } else if constexpr (EPI == EPI_ACC) {
    float* C = (float*)Cout;
#pragma unroll
    for (int r = 0; r < 4; r++) {
      const size_t ix = (size_t)(r0 + r) * ldc + c;
      C[ix] += v[r] + bv;
    }
  } else if constexpr (EPI == EPI_GELU) {
    bf16_t* C = (bf16_t*)Cout;
#pragma unroll
    for (int r = 0; r < 4; r++) {
      const float h = v[r] + bv;
      C[(size_t)(r0 + r) * ldc + c] = (bf16_t)(0.5f * h * (1.f + erff(h * 0.70710678118654752f)));
    }
  } else {  // EPI_TRANS: batched C^T: out[b][c][n]
    const int b = r0 >> t_bshift;
    const int n = r0 & ((1 << t_bshift) - 1);
    bf16_t* C = (bf16_t*)Cout + (size_t)b * t_bstride + (size_t)c * t_ld + n;
    bf16x4 o;
#pragma unroll
    for (int r = 0; r < 4; r++) o[r] = (bf16_t)(v[r] + bv);
    *(bf16x4*)C = o;
  }
}

// ---------------- gemm_bt: 128x128 tile, 4 waves, BK=32 (proven r2 kernel + batch-B) ------
template <int EPI>
__global__ __launch_bounds__(256) void gemm_bt(
    const bf16_t* __restrict__ A, const bf16_t* __restrict__ B,
    const float* __restrict__ bias, void* __restrict__ Cout,
    const float* __restrict__ Xres,
    int nK, int lda, int ldb, int ldc, float scale,
    int bsh, size_t bstr, int t_ld, int t_bshift, size_t t_bstride) {
  __shared__ __align__(16) bf16_t As[2][128 * 32];
  __shared__ __align__(16) bf16_t Bs[2][128 * 32];
  const int tid = threadIdx.x;
  int bx = blockIdx.x, by = blockIdx.y;
  xcd_remap(bx, by);
  const int m0 = by * 128, n0 = bx * 128;
  const int wave = tid >> 6, lane = tid & 63, l15 = lane & 15, hi = lane >> 4;
  const int wm = wave >> 1, wn = wave & 1;
  const int srow = tid >> 2, scol = (tid & 3) << 3;

  const bf16_t* Bb = bsh ? (B + (size_t)(m0 >> bsh) * bstr) : B;
  const bf16_t* ga = A + (size_t)(m0 + srow) * lda + scol;
  const bf16_t* gb = Bb + (size_t)(n0 + srow) * ldb + scol;
  const int lo = wave * 512;

  f32x4 acc[4][4];
#pragma unroll
  for (int i = 0; i < 4; i++)
#pragma unroll
    for (int j = 0; j < 4; j++) acc[i][j] = 0.0f;

  auto stage = [&](int buf, int kt) {
    const bf16_t* a = ga + (size_t)kt * 32;
    const bf16_t* b = gb + (size_t)kt * 32;
    async_load16(a, &As[buf][lo]);
    async_load16(a + (size_t)64 * lda, &As[buf][2048 + lo]);
    async_load16(b, &Bs[buf][lo]);
    async_load16(b + (size_t)64 * ldb, &Bs[buf][2048 + lo]);
  };

  auto compute = [&](int buf) {
    bf16x8 af[4], bg[4];
#pragma unroll
    for (int i = 0; i < 4; i++)
      af[i] = *(const bf16x8*)&As[buf][(wm * 64 + i * 16 + l15) * 32 + hi * 8];
#pragma unroll
    for (int j = 0; j < 4; j++)
      bg[j] = *(const bf16x8*)&Bs[buf][(wn * 64 + j * 16 + l15) * 32 + hi * 8];
#pragma unroll
    for (int i = 0; i < 4; i++)
#pragma unroll
      for (int j = 0; j < 4; j++)
        acc[i][j] = __builtin_amdgcn_mfma_f32_16x16x32_bf16(af[i], bg[j], acc[i][j], 0, 0, 0);
  };

  stage(0, 0);
  __syncthreads();
  for (int kt = 0; kt < nK; ++kt) {
    if (kt + 1 < nK) stage((kt + 1) & 1, kt + 1);
    compute(kt & 1);
    __syncthreads();
  }

#pragma unroll
  for (int i = 0; i < 4; i++) {
    const int r0 = m0 + wm * 64 + i * 16 + hi * 4;
#pragma unroll
    for (int j = 0; j < 4; j++) {
      const int c = n0 + wn * 64 + j * 16 + l15;
      epi_frag<EPI>(acc[i][j], r0, c, bias, Cout, Xres, ldc, scale, t_ld, t_bshift, t_bstride);
    }
  }
}

// ---------------- gemm8: 256x256 tile, 8 waves, BK=64, 8-phase, 1-tile-ahead prefetch -----
// iter k: reads LDS buffer k&1, stages tile k+1 halves (g=4k+4+q) into buffer (k&1)^1.
// vmcnt(2) at q=0 keeps only the just-issued half-stage in flight (counted, never 0 mid-loop).
template <int EPI>
__global__ __launch_bounds__(512, 2) void gemm8(
    const bf16_t* __restrict__ A, const bf16_t* __restrict__ B,
    const float* __restrict__ bias, void* __restrict__ Cout,
    const float* __restrict__ Xres,
    int nT, int lda, int ldb, int ldc, float scale,
    int bsh, size_t bstr, int t_ld, int t_bshift, size_t t_bstride) {
  __shared__ __align__(16) bf16_t As[2][256 * 64];
  __shared__ __align__(16) bf16_t Bs[2][256 * 64];
  const int tid = threadIdx.x;
  int bx = blockIdx.x, by = blockIdx.y;
  xcd_remap(bx, by);
  const int m0 = by * 256, n0 = bx * 256;
  const int wave = tid >> 6, lane = tid & 63, l15 = lane & 15, hi = lane >> 4;
  const int wm = wave >> 2, wn = wave & 3;  // 2 x 4 waves; per-wave 128x64 output

  // staging: thread covers row tid>>3 (of 64-row group), 16B chunk tid&7, source pre-swizzled
  const int srow = tid >> 3;
  const int scol = ((tid & 7) ^ (srow & 7)) << 3;
  const bf16_t* Bb = bsh ? (B + (size_t)(m0 >> bsh) * bstr) : B;
  const bf16_t* gA = A + (size_t)(m0 + srow) * lda + scol;
  const bf16_t* gB = Bb + (size_t)(n0 + srow) * ldb + scol;
  const int ldst = wave * 512;  // wave-uniform LDS base within 64-row section

  f32x4 acc[8][4];
#pragma unroll
  for (int i = 0; i < 8; i++)
#pragma unroll
    for (int j = 0; j < 4; j++) acc[i][j] = 0.0f;

  const int gmax = 4 * nT;  // total half-stages
  // half g: tile g>>2 (buffer (g>>2)&1), kind g&3 in {A-low, B-low, A-high, B-high}
  auto stage_g = [&](int g) {
    if (g >= gmax) return;
    const int t = g >> 2, buf = t & 1, h = g & 3;
    const size_t kof = (size_t)t * 64;
    if ((h & 1) == 0) {
      const int r0 = (h == 2) ? 128 : 0;
      async_load16(gA + (size_t)r0 * lda + kof, &As[buf][r0 * 64 + ldst]);
      async_load16(gA + (size_t)(r0 + 64) * lda + kof, &As[buf][(r0 + 64) * 64 + ldst]);
    } else {
      const int r0 = (h == 3) ? 128 : 0;
      async_load16(gB + (size_t)r0 * ldb + kof, &Bs[buf][r0 * 64 + ldst]);
      async_load16(gB + (size_t)(r0 + 64) * ldb + kof, &Bs[buf][(r0 + 64) * 64 + ldst]);
    }
  };

  bf16x8 af[4][2], bg[2][2];
  auto LDQ = [&](int buf, int mh, int nh) {
#pragma unroll
    for (int i = 0; i < 4; i++) {
      const int r = wm * 128 + (mh * 4 + i) * 16 + l15;
      const int rx = r & 7;
#pragma unroll
      for (int ks = 0; ks < 2; ks++)
        af[i][ks] = *(const bf16x8*)&As[buf][r * 64 + (((hi + 4 * ks) ^ rx) << 3)];
    }
#pragma unroll
    for (int j = 0; j < 2; j++) {
      const int r = wn * 64 + (nh * 2 + j) * 16 + l15;
      const int rx = r & 7;
#pragma unroll
      for (int ks = 0; ks < 2; ks++)
        bg[j][ks] = *(const bf16x8*)&Bs[buf][r * 64 + (((hi + 4 * ks) ^ rx) << 3)];
    }
  };
  auto MM = [&](int mh, int nh) {
    __builtin_amdgcn_s_setprio(1);
#pragma unroll
    for (int i = 0; i < 4; i++)
#pragma unroll
      for (int j = 0; j < 2; j++)
#pragma unroll
        for (int ks = 0; ks < 2; ks++)
          acc[mh * 4 + i][nh * 2 + j] = __builtin_amdgcn_mfma_f32_16x16x32_bf16(
              af[i][ks], bg[j][ks], acc[mh * 4 + i][nh * 2 + j], 0, 0, 0);
    __builtin_amdgcn_s_setprio(0);
  };

  // prologue: tile 0's four halves
  for (int g = 0; g < 4; ++g) stage_g(g);

  for (int k = 0; k < nT; ++k) {
    const int buf = k & 1;
    const int s4 = 4 * k + 4;  // tile k+1 halves
    // phase q=0 (quadrant mh0,nh0)
    stage_g(s4 + 0);
    if (k + 1 < nT) { VM2; } else { VM0; }
    BAR;
    LDQ(buf, 0, 0);
    MM(0, 0);
    BAR;
    // q=1 (mh0,nh1)
    LDQ(buf, 0, 1);
    stage_g(s4 + 1);
    BAR;
    MM(0, 1);
    BAR;
    // q=2 (mh1,nh0)
    LDQ(buf, 1, 0);
    stage_g(s4 + 2);
    BAR;
    MM(1, 0);
    BAR;
    // q=3 (mh1,nh1)
    LDQ(buf, 1, 1);
    stage_g(s4 + 3);
    BAR;
    MM(1, 1);
    BAR;
  }

#pragma unroll
  for (int fi = 0; fi < 8; fi++) {
    const int r0 = m0 + wm * 128 + fi * 16 + hi * 4;
#pragma unroll
    for (int fj = 0; fj < 4; fj++) {
      const int c = n0 + wn * 64 + fj * 16 + l15;
      epi_frag<EPI>(acc[fi][fj], r0, c, bias, Cout, Xres, ldc, scale, t_ld, t_bshift, t_bstride);
    }
  }
}

// ---------------- host ----------------
extern "C" void kernel_launch(void* const* d_in, const int* in_sizes, int n_in,
                              void* d_out, int out_size, void* d_ws, size_t ws_size,
                              hipStream_t stream) {
  (void)in_sizes; (void)n_in; (void)out_size; (void)ws_size;
  const float* x   = (const float*)d_in[0];
  const float* te  = (const float*)d_in[1];
  const float* sqw = (const float*)d_in[2];
  const float* skw = (const float*)d_in[3];
  const float* cqw = (const float*)d_in[4];
  const float* ckw = (const float*)d_in[5];
  const float* lnw = (const float*)d_in[6];
  const float* lnb = (const float*)d_in[7];
  const float* Wq = (const float*)d_in[8];  const float* bq = (const float*)d_in[9];
  const float* Wk = (const float*)d_in[10]; const float* bk = (const float*)d_in[11];
  const float* Wv = (const float*)d_in[12]; const float* bv = (const float*)d_in[13];
  const float* Wo = (const float*)d_in[14]; const float* bo = (const float*)d_in[15];
  const float* CWq = (const float*)d_in[16]; const float* Cbq = (const float*)d_in[17];
  const float* CWk = (const float*)d_in[18]; const float* Cbk = (const float*)d_in[19];
  const float* CWv = (const float*)d_in[20]; const float* Cbv = (const float*)d_in[21];
  const float* CWo = (const float*)d_in[22]; const float* Cbo = (const float*)d_in[23];
  const float* W1 = (const float*)d_in[24]; const float* b1 = (const float*)d_in[25];
  const float* W2 = (const float*)d_in[26]; const float* b2 = (const float*)d_in[27];
  float* out = (float*)d_out;

  // ---- arena (bf16 element offsets); peak ~170 MB ----
  bf16_t* ws = (bf16_t*)d_ws;
  bf16_t* WT0  = ws;                 // 9437184 el (DD*FF)
  bf16_t* WT1  = ws + 9437184;       // 9437184 el
  bf16_t* Cx   = ws + 18874368;      // 12582912 el: xr -> cross-pre
  bf16_t* Tb   = ws + 31457280;      // 1572864
  bf16_t* Tck  = ws + 33030144;      // 1572864
  bf16_t* QK   = ws + 34603008;      // 25165824: xb -> Q|K (ldc 3072) -> PVout -> LNout
  bf16_t* CK   = ws + 47185920;      // 1572864 (upper half of QK region)
  bf16_t* Vt   = ws + 59768832;      // 12582912: V^T -> CV^T -> H(part)
  bf16_t* CQ   = ws + 72351744;      // 12582912: CQ -> H(part)
  bf16_t* S    = ws;                 // 33554432 el overlay during self-attn
  bf16_t* Sc   = ws;                 // 4194304 el overlay (cross scores)
  bf16_t* PVo  = QK;                 // alias
  bf16_t* LNo  = QK;                 // alias
  bf16_t* H    = Vt;                 // 25165824 el (covers Vt+CQ)
  float* biascat = (float*)(ws + 84934656);  // 3072 f32

  const dim3 blk(256), blk8(512), tb(32, 8);
  const float scl = 0.025515518153991442f;  // 1/sqrt(1536)

  auto T = [&](const float* W, bf16_t* Wt, int K, int N, const float* s) {
    transpose_to_bf16<<<dim3(N / 32, K / 32), tb, 0, stream>>>(W, Wt, K, N, s);
  };
  auto g8 = [](int M, int N) { return dim3(N / 256, M / 256); };
  auto g4 = [](int M, int N) { return dim3(N / 128, M / 128); };

  // bias concat bq|bk
  hipMemcpyAsync(biascat, bq, DD * sizeof(float), hipMemcpyDeviceToDevice, stream);
  hipMemcpyAsync(biascat + DD, bk, DD * sizeof(float), hipMemcpyDeviceToDevice, stream);

  // norms for x (shared rms factor; weights folded into transposed W)
  norm_x2<<<8192, blk, 0, stream>>>(x, Cx, QK /*xb*/);

  // V projection (raw x), V^T batched
  T(Wv, WT0, DD, DD, nullptr);
  gemm8<EPI_TRANS><<<g8(8192, DD), blk8, 0, stream>>>(QK /*xb*/, WT0, bv, Vt, nullptr,
      24, DD, DD, 0, 1.f, 0, 0, 4096, 12, (size_t)DD * 4096);

  // merged Q|K projection + CQ projection (norm weights folded)
  T(Wq, WT1, DD, DD, sqw);
  T(Wk, WT1 + 2359296, DD, DD, skw);
  T(CWq, WT1 + 4718592, DD, DD, cqw);
  gemm8<EPI_BF16><<<g8(8192, 3072), blk8, 0, stream>>>(Cx, WT1, biascat, QK, nullptr,
      24, DD, DD, 3072, 1.f, 0, 0, 0, 0, 0);
  gemm8<EPI_BF16><<<g8(8192, DD), blk8, 0, stream>>>(Cx, WT1 + 4718592, Cbq, CQ, nullptr,
      24, DD, DD, DD, 1.f, 0, 0, 0, 0, 0);

  // self-attention, both batches in one dispatch (B selected via m0>>12)
  gemm8<EPI_BF16S><<<g8(8192, 4096), blk8, 0, stream>>>(QK /*Q*/, QK + DD /*K*/, nullptr, S, nullptr,
      24, 3072, 3072, 4096, scl, 12, (size_t)4096 * 3072, 0, 0, 0);
  softmax_bf16<4096><<<8192, blk, 0, stream>>>(S);
  gemm8<EPI_BF16><<<g8(8192, DD), blk8, 0, stream>>>(S, Vt, nullptr, PVo, nullptr,
      64, 4096, 4096, DD, 1.f, 12, (size_t)DD * 4096, 0, 0, 0);
  T(Wo, WT0, DD, DD, nullptr);
  gemm8<EPI_ADD_X><<<g8(8192, DD), blk8, 0, stream>>>(PVo, WT0, bo, out, x,
      24, DD, DD, DD, 1.f, 0, 0, 0, 0, 0);

  // cross-attention
  norm_t2<<<1024, blk, 0, stream>>>(te, Tb, Tck);
  T(CWk, WT1, DD, DD, ckw);
  gemm_bt<EPI_BF16><<<g4(1024, DD), blk, 0, stream>>>(Tck, WT1, Cbk, CK, nullptr,
      48, DD, DD, DD, 1.f, 0, 0, 0, 0, 0);
  T(CWv, WT0, DD, DD, nullptr);
  gemm_bt<EPI_TRANS><<<g4(1024, DD), blk, 0, stream>>>(Tb, WT0, Cbv, Vt, nullptr,
      48, DD, DD, 0, 1.f, 0, 0, 512, 9, (size_t)DD * 512);
  gemm_bt<EPI_BF16S><<<g4(8192, 512), blk, 0, stream>>>(CQ, CK, nullptr, Sc, nullptr,
      48, DD, DD, 512, scl, 12, (size_t)512 * DD, 0, 0, 0);
  softmax_bf16<512><<<8192, blk, 0, stream>>>(Sc);
  gemm8<EPI_BF16><<<g8(8192, DD), blk8, 0, stream>>>(Sc, Vt, nullptr, Cx, nullptr,
      8, 512, 512, DD, 1.f, 12, (size_t)DD * 512, 0, 0, 0);
  T(CWo, WT1, DD, DD, nullptr);
  gemm8<EPI_ACC><<<g8(8192, DD), blk8, 0, stream>>>(Cx, WT1, Cbo, out, nullptr,
      24, DD, DD, DD, 1.f, 0, 0, 0, 0, 0);

  // FFN: LN -> W1(+gelu) in 2 column chunks of 3072 -> W2 acc
  norm_ln<<<8192, blk, 0, stream>>>(x, lnw, lnb, LNo);
  T(W1, WT0, DD, FF, nullptr);
  T(W2, WT1, FF, DD, nullptr);
  for (int c = 0; c < 2; c++) {
    gemm8<EPI_GELU><<<g8(8192, 3072), blk8, 0, stream>>>(LNo, WT0 + (size_t)c * 4718592,
        b1 + c * 3072, H, nullptr, 24, DD, DD, 3072, 1.f, 0, 0, 0, 0, 0);
    gemm8<EPI_ACC><<<g8(8192, DD), blk8, 0, stream>>>(H, WT1 + c * 3072,
        (c == 0) ? b2 : nullptr, out, nullptr, 48, 3072, FF, DD, 1.f, 0, 0, 0, 0, 0);
  }
}

// Round 5
// 1427.385 us; speedup vs baseline: 1.2355x; 1.0902x over previous
//
#include <hip/hip_runtime.h>
#include <hip/hip_bf16.h>
#include <cmath>

#define DD 1536
#define FF 6144

typedef __bf16 bf16_t;
typedef __bf16 bf16x8 __attribute__((ext_vector_type(8)));
typedef __bf16 bf16x4 __attribute__((ext_vector_type(4)));
typedef float  f32x4  __attribute__((ext_vector_type(4)));

#define VM2 asm volatile("s_waitcnt vmcnt(2)" ::: "memory")
#define VM0 asm volatile("s_waitcnt vmcnt(0)" ::: "memory")
#define BAR __builtin_amdgcn_s_barrier()

__device__ __forceinline__ void async_load16(const bf16_t* g, bf16_t* l) {
  __builtin_amdgcn_global_load_lds(
      (const __attribute__((address_space(1))) void*)g,
      (__attribute__((address_space(3))) void*)l, 16, 0, 0);
}

// bijective XCD-aware remap (m204)
__device__ __forceinline__ void xcd_remap(int& bx, int& by) {
  const int gx = gridDim.x, gy = gridDim.y;
  int wg = by * gx + bx;
  const int nwg = gx * gy;
  const int q = nwg >> 3, r = nwg & 7, xcd = wg & 7, o = wg >> 3;
  wg = (xcd < r ? xcd * (q + 1) : r * (q + 1) + (xcd - r) * q) + o;
  bx = wg % gx;
  by = wg / gx;
}

// ---------------- weight fp32 -> bf16 transpose, optional per-K row scale ----------------
__global__ __launch_bounds__(256) void transpose_to_bf16(
    const float* __restrict__ W, bf16_t* __restrict__ Wt, int K, int N,
    const float* __restrict__ s) {
  __shared__ float tile[32][33];
  const int tx = threadIdx.x, ty = threadIdx.y;  // 32 x 8
  const int n0 = blockIdx.x * 32, k0 = blockIdx.y * 32;
#pragma unroll
  for (int i = 0; i < 4; i++)
    tile[ty + 8 * i][tx] = W[(size_t)(k0 + ty + 8 * i) * N + n0 + tx];
  __syncthreads();
  const float sc = (s != nullptr) ? s[k0 + tx] : 1.f;
#pragma unroll
  for (int i = 0; i < 4; i++)
    Wt[(size_t)(n0 + ty + 8 * i) * K + k0 + tx] = (bf16_t)(tile[tx][ty + 8 * i] * sc);
}

// ---------------- reduction helpers ----------------
__device__ __forceinline__ void breduce1(float& a) {
#pragma unroll
  for (int off = 32; off; off >>= 1) a += __shfl_xor(a, off);
  __shared__ float sa[4];
  const int w = threadIdx.x >> 6, ln = threadIdx.x & 63;
  if (ln == 0) sa[w] = a;
  __syncthreads();
  a = (sa[0] + sa[1]) + (sa[2] + sa[3]);
  __syncthreads();
}

__device__ __forceinline__ void breduce2(float& a, float& b) {
#pragma unroll
  for (int off = 32; off; off >>= 1) {
    a += __shfl_xor(a, off);
    b += __shfl_xor(b, off);
  }
  __shared__ float sa[4], sb[4];
  const int w = threadIdx.x >> 6, ln = threadIdx.x & 63;
  if (ln == 0) { sa[w] = a; sb[w] = b; }
  __syncthreads();
  a = (sa[0] + sa[1]) + (sa[2] + sa[3]);
  b = (sb[0] + sb[1]) + (sb[2] + sb[3]);
  __syncthreads();
}

// ---------------- x: shared rms factor -> xr = x*rq (bf16), xb = x (bf16) ----------------
__global__ __launch_bounds__(256) void norm_x2(
    const float* __restrict__ x, bf16_t* __restrict__ xr, bf16_t* __restrict__ xb) {
  const int row = blockIdx.x, t = threadIdx.x;
  const float* p = x + (size_t)row * DD;
  f32x4 v0 = ((const f32x4*)p)[t];
  f32x4 v1 = 0.0f;
  if (t < 128) v1 = ((const f32x4*)p)[256 + t];
  float s2 = 0.f;
#pragma unroll
  for (int e = 0; e < 4; e++) s2 += v0[e] * v0[e];
  if (t < 128) {
#pragma unroll
    for (int e = 0; e < 4; e++) s2 += v1[e] * v1[e];
  }
  breduce1(s2);
  const float rq = rsqrtf(s2 * (1.f / DD) + 1e-7f);
  auto emit = [&](int ci, f32x4 v) {
    bf16x4 orr, ob;
#pragma unroll
    for (int e = 0; e < 4; e++) {
      orr[e] = (bf16_t)(v[e] * rq);
      ob[e] = (bf16_t)v[e];
    }
    const size_t o = (size_t)row * DD + ci * 4;
    *(bf16x4*)(xr + o) = orr;
    *(bf16x4*)(xb + o) = ob;
  };
  emit(t, v0);
  if (t < 128) emit(256 + t, v1);
}

// ---------------- LayerNorm -> bf16 ----------------
__global__ __launch_bounds__(256) void norm_ln(
    const float* __restrict__ x, const float* __restrict__ w,
    const float* __restrict__ bb, bf16_t* __restrict__ o) {
  const int row = blockIdx.x, t = threadIdx.x;
  const float* p = x + (size_t)row * DD;
  f32x4 v0 = ((const f32x4*)p)[t];
  f32x4 v1 = 0.0f;
  if (t < 128) v1 = ((const f32x4*)p)[256 + t];
  float s = 0.f, s2 = 0.f;
#pragma unroll
  for (int e = 0; e < 4; e++) { s += v0[e]; s2 += v0[e] * v0[e]; }
  if (t < 128) {
#pragma unroll
    for (int e = 0; e < 4; e++) { s += v1[e]; s2 += v1[e] * v1[e]; }
  }
  breduce2(s, s2);
  const float mu = s * (1.f / DD);
  const float rln = rsqrtf(s2 * (1.f / DD) - mu * mu + 1e-5f);
  auto emit = [&](int ci, f32x4 v) {
    const int i0 = ci * 4;
    bf16x4 ov;
#pragma unroll
    for (int e = 0; e < 4; e++)
      ov[e] = (bf16_t)((v[e] - mu) * rln * w[i0 + e] + bb[i0 + e]);
    *(bf16x4*)(o + (size_t)row * DD + i0) = ov;
  };
  emit(t, v0);
  if (t < 128) emit(256 + t, v1);
}

// ---------------- text: Tb = raw bf16, Tck = text*rtq (ck_w folded into weight) ----------
__global__ __launch_bounds__(256) void norm_t2(
    const float* __restrict__ te, bf16_t* __restrict__ tb, bf16_t* __restrict__ tck) {
  const int row = blockIdx.x, t = threadIdx.x;
  const float* p = te + (size_t)row * DD;
  f32x4 v0 = ((const f32x4*)p)[t];
  f32x4 v1 = 0.0f;
  if (t < 128) v1 = ((const f32x4*)p)[256 + t];
  float s2 = 0.f;
#pragma unroll
  for (int e = 0; e < 4; e++) s2 += v0[e] * v0[e];
  if (t < 128) {
#pragma unroll
    for (int e = 0; e < 4; e++) s2 += v1[e] * v1[e];
  }
  breduce1(s2);
  const float rq = rsqrtf(s2 * (1.f / DD) + 1e-7f);
  auto emit = [&](int ci, f32x4 v) {
    bf16x4 ob, oc;
#pragma unroll
    for (int e = 0; e < 4; e++) {
      ob[e] = (bf16_t)v[e];
      oc[e] = (bf16_t)(v[e] * rq);
    }
    const size_t o = (size_t)row * DD + ci * 4;
    *(bf16x4*)(tb + o) = ob;
    *(bf16x4*)(tck + o) = oc;
  };
  emit(t, v0);
  if (t < 128) emit(256 + t, v1);
}

// ---------------- in-place bf16 row softmax ----------------
template <int NC>
__global__ __launch_bounds__(256) void softmax_bf16(bf16_t* __restrict__ S) {
  const int t = threadIdx.x;
  bf16_t* sr = S + (size_t)blockIdx.x * NC;
  constexpr int NV = (NC / 8 + 255) / 256;
  float v[NV][8];
  float mx = -3.4e38f;
#pragma unroll
  for (int i = 0; i < NV; i++) {
    const int idx = t + i * 256;
    if (idx * 8 < NC) {
      bf16x8 b = ((const bf16x8*)sr)[idx];
#pragma unroll
      for (int e = 0; e < 8; e++) {
        v[i][e] = (float)b[e];
        mx = fmaxf(mx, v[i][e]);
      }
    }
  }
#pragma unroll
  for (int off = 32; off; off >>= 1) mx = fmaxf(mx, __shfl_xor(mx, off));
  __shared__ float sm[4];
  const int w = t >> 6, ln = t & 63;
  if (ln == 0) sm[w] = mx;
  __syncthreads();
  mx = fmaxf(fmaxf(sm[0], sm[1]), fmaxf(sm[2], sm[3]));
  __syncthreads();
  float sum = 0.f;
#pragma unroll
  for (int i = 0; i < NV; i++) {
    const int idx = t + i * 256;
    if (idx * 8 < NC) {
#pragma unroll
      for (int e = 0; e < 8; e++) {
        v[i][e] = __expf(v[i][e] - mx);
        sum += v[i][e];
      }
    }
  }
#pragma unroll
  for (int off = 32; off; off >>= 1) sum += __shfl_xor(sum, off);
  __shared__ float ss[4];
  if (ln == 0) ss[w] = sum;
  __syncthreads();
  sum = (ss[0] + ss[1]) + (ss[2] + ss[3]);
  const float inv = 1.f / sum;
#pragma unroll
  for (int i = 0; i < NV; i++) {
    const int idx = t + i * 256;
    if (idx * 8 < NC) {
      bf16x8 o;
#pragma unroll
      for (int e = 0; e < 8; e++) o[e] = (bf16_t)(v[i][e] * inv);
      ((bf16x8*)sr)[idx] = o;
    }
  }
}

enum { EPI_BF16 = 0, EPI_F32_SCALE = 1, EPI_ADD_X = 2, EPI_ACC = 3, EPI_GELU = 4, EPI_TRANS = 5, EPI_BF16S = 6 };

// shared epilogue write for one 4-row fragment column
template <int EPI>
__device__ __forceinline__ void epi_frag(
    f32x4 v, int r0, int c, const float* bias, void* Cout, const float* Xres,
    int ldc, float scale, int t_ld, int t_bshift, size_t t_bstride) {
  const float bv = (bias != nullptr) ? bias[c] : 0.f;
  if constexpr (EPI == EPI_BF16) {
    bf16_t* C = (bf16_t*)Cout;
#pragma unroll
    for (int r = 0; r < 4; r++) C[(size_t)(r0 + r) * ldc + c] = (bf16_t)(v[r] + bv);
  } else if constexpr (EPI == EPI_F32_SCALE) {
    float* C = (float*)Cout;
#pragma unroll
    for (int r = 0; r < 4; r++) C[(size_t)(r0 + r) * ldc + c] = v[r] * scale;
  } else if constexpr (EPI == EPI_BF16S) {
    bf16_t* C = (bf16_t*)Cout;
#pragma unroll
    for (int r = 0; r < 4; r++) C[(size_t)(r0 + r) * ldc + c] = (bf16_t)(v[r] * scale);
  } else if constexpr (EPI == EPI_ADD_X) {
    float* C = (float*)Cout;
#pragma unroll
    for (int r = 0; r < 4; r++) {
      const size_t ix = (size_t)(r0 + r) * ldc + c;
      C[ix] = Xres[ix] + v[r] + bv;
    }
  } else if constexpr (EPI == EPI_ACC) {
    float* C = (float*)Cout;
#pragma unroll
    for (int r = 0; r < 4; r++) {
      const size_t ix = (size_t)(r0 + r) * ldc + c;
      C[ix] += v[r] + bv;
    }
  } else if constexpr (EPI == EPI_GELU) {
    bf16_t* C = (bf16_t*)Cout;
#pragma unroll
    for (int r = 0; r < 4; r++) {
      const float h = v[r] + bv;
      C[(size_t)(r0 + r) * ldc + c] = (bf16_t)(0.5f * h * (1.f + erff(h * 0.70710678118654752f)));
    }
  } else {  // EPI_TRANS: batched C^T: out[b][c][n]
    const int b = r0 >> t_bshift;
    const int n = r0 & ((1 << t_bshift) - 1);
    bf16_t* C = (bf16_t*)Cout + (size_t)b * t_bstride + (size_t)c * t_ld + n;
    bf16x4 o;
#pragma unroll
    for (int r = 0; r < 4; r++) o[r] = (bf16_t)(v[r] + bv);
    *(bf16x4*)C = o;
  }
}

// ---------------- gemm_bt: 128x128 tile, 4 waves, BK=32 (proven r2 kernel + batch-B) ------
template <int EPI>
__global__ __launch_bounds__(256) void gemm_bt(
    const bf16_t* __restrict__ A, const bf16_t* __restrict__ B,
    const float* __restrict__ bias, void* __restrict__ Cout,
    const float* __restrict__ Xres,
    int nK, int lda, int ldb, int ldc, float scale,
    int bsh, size_t bstr, int t_ld, int t_bshift, size_t t_bstride) {
  __shared__ __align__(16) bf16_t As[2][128 * 32];
  __shared__ __align__(16) bf16_t Bs[2][128 * 32];
  const int tid = threadIdx.x;
  int bx = blockIdx.x, by = blockIdx.y;
  xcd_remap(bx, by);
  const int m0 = by * 128, n0 = bx * 128;
  const int wave = tid >> 6, lane = tid & 63, l15 = lane & 15, hi = lane >> 4;
  const int wm = wave >> 1, wn = wave & 1;
  const int srow = tid >> 2, scol = (tid & 3) << 3;

  const bf16_t* Bb = bsh ? (B + (size_t)(m0 >> bsh) * bstr) : B;
  const bf16_t* ga = A + (size_t)(m0 + srow) * lda + scol;
  const bf16_t* gb = Bb + (size_t)(n0 + srow) * ldb + scol;
  const int lo = wave * 512;

  f32x4 acc[4][4];
#pragma unroll
  for (int i = 0; i < 4; i++)
#pragma unroll
    for (int j = 0; j < 4; j++) acc[i][j] = 0.0f;

  auto stage = [&](int buf, int kt) {
    const bf16_t* a = ga + (size_t)kt * 32;
    const bf16_t* b = gb + (size_t)kt * 32;
    async_load16(a, &As[buf][lo]);
    async_load16(a + (size_t)64 * lda, &As[buf][2048 + lo]);
    async_load16(b, &Bs[buf][lo]);
    async_load16(b + (size_t)64 * ldb, &Bs[buf][2048 + lo]);
  };

  auto compute = [&](int buf) {
    bf16x8 af[4], bg[4];
#pragma unroll
    for (int i = 0; i < 4; i++)
      af[i] = *(const bf16x8*)&As[buf][(wm * 64 + i * 16 + l15) * 32 + hi * 8];
#pragma unroll
    for (int j = 0; j < 4; j++)
      bg[j] = *(const bf16x8*)&Bs[buf][(wn * 64 + j * 16 + l15) * 32 + hi * 8];
#pragma unroll
    for (int i = 0; i < 4; i++)
#pragma unroll
      for (int j = 0; j < 4; j++)
        acc[i][j] = __builtin_amdgcn_mfma_f32_16x16x32_bf16(af[i], bg[j], acc[i][j], 0, 0, 0);
  };

  stage(0, 0);
  __syncthreads();
  for (int kt = 0; kt < nK; ++kt) {
    if (kt + 1 < nK) stage((kt + 1) & 1, kt + 1);
    compute(kt & 1);
    __syncthreads();
  }

#pragma unroll
  for (int i = 0; i < 4; i++) {
    const int r0 = m0 + wm * 64 + i * 16 + hi * 4;
#pragma unroll
    for (int j = 0; j < 4; j++) {
      const int c = n0 + wn * 64 + j * 16 + l15;
      epi_frag<EPI>(acc[i][j], r0, c, bias, Cout, Xres, ldc, scale, t_ld, t_bshift, t_bstride);
    }
  }
}

// ---------------- gemm8: 256x256 tile, 8 waves, BK=64, 8-phase, 1-tile-ahead prefetch -----
// iter k: reads LDS buffer k&1, stages tile k+1 halves (g=4k+4+q) into buffer (k&1)^1.
// Fragment reuse: af depends only on mh, bg only on nh -> 24 ds_read_b128 per K-tile
// (q0: af0+bg0, q1: bg1, q2: af1, q3: none) instead of 48. LDS-pipe was the bottleneck.
template <int EPI>
__global__ __launch_bounds__(512, 2) void gemm8(
    const bf16_t* __restrict__ A, const bf16_t* __restrict__ B,
    const float* __restrict__ bias, void* __restrict__ Cout,
    const float* __restrict__ Xres,
    int nT, int lda, int ldb, int ldc, float scale,
    int bsh, size_t bstr, int t_ld, int t_bshift, size_t t_bstride) {
  __shared__ __align__(16) bf16_t As[2][256 * 64];
  __shared__ __align__(16) bf16_t Bs[2][256 * 64];
  const int tid = threadIdx.x;
  int bx = blockIdx.x, by = blockIdx.y;
  xcd_remap(bx, by);
  const int m0 = by * 256, n0 = bx * 256;
  const int wave = tid >> 6, lane = tid & 63, l15 = lane & 15, hi = lane >> 4;
  const int wm = wave >> 2, wn = wave & 3;  // 2 x 4 waves; per-wave 128x64 output

  // staging: thread covers row tid>>3 (of 64-row group), 16B chunk tid&7, source pre-swizzled
  const int srow = tid >> 3;
  const int scol = ((tid & 7) ^ (srow & 7)) << 3;
  const bf16_t* Bb = bsh ? (B + (size_t)(m0 >> bsh) * bstr) : B;
  const bf16_t* gA = A + (size_t)(m0 + srow) * lda + scol;
  const bf16_t* gB = Bb + (size_t)(n0 + srow) * ldb + scol;
  const int ldst = wave * 512;  // wave-uniform LDS base within 64-row section

  f32x4 acc[8][4];
#pragma unroll
  for (int i = 0; i < 8; i++)
#pragma unroll
    for (int j = 0; j < 4; j++) acc[i][j] = 0.0f;

  const int gmax = 4 * nT;  // total half-stages
  // half g: tile g>>2 (buffer (g>>2)&1), kind g&3 in {A-low, B-low, A-high, B-high}
  auto stage_g = [&](int g) {
    if (g >= gmax) return;
    const int t = g >> 2, buf = t & 1, h = g & 3;
    const size_t kof = (size_t)t * 64;
    if ((h & 1) == 0) {
      const int r0 = (h == 2) ? 128 : 0;
      async_load16(gA + (size_t)r0 * lda + kof, &As[buf][r0 * 64 + ldst]);
      async_load16(gA + (size_t)(r0 + 64) * lda + kof, &As[buf][(r0 + 64) * 64 + ldst]);
    } else {
      const int r0 = (h == 3) ? 128 : 0;
      async_load16(gB + (size_t)r0 * ldb + kof, &Bs[buf][r0 * 64 + ldst]);
      async_load16(gB + (size_t)(r0 + 64) * ldb + kof, &Bs[buf][(r0 + 64) * 64 + ldst]);
    }
  };

  bf16x8 af[4][2], bg[2][2][2];  // af[i][ks] (current mh), bg[nh][j][ks] (both nh cached)
  auto LDA = [&](int buf, int mh) {
#pragma unroll
    for (int i = 0; i < 4; i++) {
      const int r = wm * 128 + (mh * 4 + i) * 16 + l15;
      const int rx = r & 7;
#pragma unroll
      for (int ks = 0; ks < 2; ks++)
        af[i][ks] = *(const bf16x8*)&As[buf][r * 64 + (((hi + 4 * ks) ^ rx) << 3)];
    }
  };
  auto LDB = [&](int buf, int nh) {
#pragma unroll
    for (int j = 0; j < 2; j++) {
      const int r = wn * 64 + (nh * 2 + j) * 16 + l15;
      const int rx = r & 7;
#pragma unroll
      for (int ks = 0; ks < 2; ks++)
        bg[nh][j][ks] = *(const bf16x8*)&Bs[buf][r * 64 + (((hi + 4 * ks) ^ rx) << 3)];
    }
  };
  auto MM = [&](int mh, int nh) {
    __builtin_amdgcn_s_setprio(1);
#pragma unroll
    for (int i = 0; i < 4; i++)
#pragma unroll
      for (int j = 0; j < 2; j++)
#pragma unroll
        for (int ks = 0; ks < 2; ks++)
          acc[mh * 4 + i][nh * 2 + j] = __builtin_amdgcn_mfma_f32_16x16x32_bf16(
              af[i][ks], bg[nh][j][ks], acc[mh * 4 + i][nh * 2 + j], 0, 0, 0);
    __builtin_amdgcn_s_setprio(0);
  };

  // prologue: tile 0's four halves
  for (int g = 0; g < 4; ++g) stage_g(g);

  for (int k = 0; k < nT; ++k) {
    const int buf = k & 1;
    const int s4 = 4 * k + 4;  // tile k+1 halves
    // q0 (mh0,nh0): reads af(mh0)+bg(nh0)
    stage_g(s4 + 0);
    if (k + 1 < nT) { VM2; } else { VM0; }
    BAR;
    LDA(buf, 0);
    LDB(buf, 0);
    MM(0, 0);
    BAR;
    // q1 (mh0,nh1): reads bg(nh1) only
    LDB(buf, 1);
    stage_g(s4 + 1);
    BAR;
    MM(0, 1);
    BAR;
    // q2 (mh1,nh0): reads af(mh1) only, reuses bg(nh0)
    LDA(buf, 1);
    stage_g(s4 + 2);
    BAR;
    MM(1, 0);
    BAR;
    // q3 (mh1,nh1): no LDS reads, reuses af(mh1)+bg(nh1)
    stage_g(s4 + 3);
    BAR;
    MM(1, 1);
    BAR;
  }

#pragma unroll
  for (int fi = 0; fi < 8; fi++) {
    const int r0 = m0 + wm * 128 + fi * 16 + hi * 4;
#pragma unroll
    for (int fj = 0; fj < 4; fj++) {
      const int c = n0 + wn * 64 + fj * 16 + l15;
      epi_frag<EPI>(acc[fi][fj], r0, c, bias, Cout, Xres, ldc, scale, t_ld, t_bshift, t_bstride);
    }
  }
}

// ---------------- host ----------------
extern "C" void kernel_launch(void* const* d_in, const int* in_sizes, int n_in,
                              void* d_out, int out_size, void* d_ws, size_t ws_size,
                              hipStream_t stream) {
  (void)in_sizes; (void)n_in; (void)out_size; (void)ws_size;
  const float* x   = (const float*)d_in[0];
  const float* te  = (const float*)d_in[1];
  const float* sqw = (const float*)d_in[2];
  const float* skw = (const float*)d_in[3];
  const float* cqw = (const float*)d_in[4];
  const float* ckw = (const float*)d_in[5];
  const float* lnw = (const float*)d_in[6];
  const float* lnb = (const float*)d_in[7];
  const float* Wq = (const float*)d_in[8];  const float* bq = (const float*)d_in[9];
  const float* Wk = (const float*)d_in[10]; const float* bk = (const float*)d_in[11];
  const float* Wv = (const float*)d_in[12]; const float* bv = (const float*)d_in[13];
  const float* Wo = (const float*)d_in[14]; const float* bo = (const float*)d_in[15];
  const float* CWq = (const float*)d_in[16]; const float* Cbq = (const float*)d_in[17];
  const float* CWk = (const float*)d_in[18]; const float* Cbk = (const float*)d_in[19];
  const float* CWv = (const float*)d_in[20]; const float* Cbv = (const float*)d_in[21];
  const float* CWo = (const float*)d_in[22]; const float* Cbo = (const float*)d_in[23];
  const float* W1 = (const float*)d_in[24]; const float* b1 = (const float*)d_in[25];
  const float* W2 = (const float*)d_in[26]; const float* b2 = (const float*)d_in[27];
  float* out = (float*)d_out;

  // ---- arena (bf16 element offsets); peak ~170 MB ----
  bf16_t* ws = (bf16_t*)d_ws;
  bf16_t* WT0  = ws;                 // 9437184 el (DD*FF)
  bf16_t* WT1  = ws + 9437184;       // 9437184 el
  bf16_t* Cx   = ws + 18874368;      // 12582912 el: xr -> cross-pre
  bf16_t* Tb   = ws + 31457280;      // 1572864
  bf16_t* Tck  = ws + 33030144;      // 1572864
  bf16_t* QK   = ws + 34603008;      // 25165824: xb -> Q|K (ldc 3072) -> PVout -> LNout
  bf16_t* CK   = ws + 47185920;      // 1572864 (upper half of QK region)
  bf16_t* Vt   = ws + 59768832;      // 12582912: V^T -> CV^T -> H(part)
  bf16_t* CQ   = ws + 72351744;      // 12582912: CQ -> H(part)
  bf16_t* S    = ws;                 // 33554432 el overlay during self-attn
  bf16_t* Sc   = ws;                 // 4194304 el overlay (cross scores)
  bf16_t* PVo  = QK;                 // alias
  bf16_t* LNo  = QK;                 // alias
  bf16_t* H    = Vt;                 // 25165824 el (covers Vt+CQ)
  float* biascat = (float*)(ws + 84934656);  // 3072 f32

  const dim3 blk(256), blk8(512), tb(32, 8);
  const float scl = 0.025515518153991442f;  // 1/sqrt(1536)

  auto T = [&](const float* W, bf16_t* Wt, int K, int N, const float* s) {
    transpose_to_bf16<<<dim3(N / 32, K / 32), tb, 0, stream>>>(W, Wt, K, N, s);
  };
  auto g8 = [](int M, int N) { return dim3(N / 256, M / 256); };
  auto g4 = [](int M, int N) { return dim3(N / 128, M / 128); };

  // bias concat bq|bk
  hipMemcpyAsync(biascat, bq, DD * sizeof(float), hipMemcpyDeviceToDevice, stream);
  hipMemcpyAsync(biascat + DD, bk, DD * sizeof(float), hipMemcpyDeviceToDevice, stream);

  // norms for x (shared rms factor; weights folded into transposed W)
  norm_x2<<<8192, blk, 0, stream>>>(x, Cx, QK /*xb*/);

  // V projection (raw x), V^T batched
  T(Wv, WT0, DD, DD, nullptr);
  gemm8<EPI_TRANS><<<g8(8192, DD), blk8, 0, stream>>>(QK /*xb*/, WT0, bv, Vt, nullptr,
      24, DD, DD, 0, 1.f, 0, 0, 4096, 12, (size_t)DD * 4096);

  // merged Q|K projection + CQ projection (norm weights folded)
  T(Wq, WT1, DD, DD, sqw);
  T(Wk, WT1 + 2359296, DD, DD, skw);
  T(CWq, WT1 + 4718592, DD, DD, cqw);
  gemm8<EPI_BF16><<<g8(8192, 3072), blk8, 0, stream>>>(Cx, WT1, biascat, QK, nullptr,
      24, DD, DD, 3072, 1.f, 0, 0, 0, 0, 0);
  gemm8<EPI_BF16><<<g8(8192, DD), blk8, 0, stream>>>(Cx, WT1 + 4718592, Cbq, CQ, nullptr,
      24, DD, DD, DD, 1.f, 0, 0, 0, 0, 0);

  // self-attention, both batches in one dispatch (B selected via m0>>12)
  gemm8<EPI_BF16S><<<g8(8192, 4096), blk8, 0, stream>>>(QK /*Q*/, QK + DD /*K*/, nullptr, S, nullptr,
      24, 3072, 3072, 4096, scl, 12, (size_t)4096 * 3072, 0, 0, 0);
  softmax_bf16<4096><<<8192, blk, 0, stream>>>(S);
  gemm8<EPI_BF16><<<g8(8192, DD), blk8, 0, stream>>>(S, Vt, nullptr, PVo, nullptr,
      64, 4096, 4096, DD, 1.f, 12, (size_t)DD * 4096, 0, 0, 0);
  T(Wo, WT0, DD, DD, nullptr);
  gemm8<EPI_ADD_X><<<g8(8192, DD), blk8, 0, stream>>>(PVo, WT0, bo, out, x,
      24, DD, DD, DD, 1.f, 0, 0, 0, 0, 0);

  // cross-attention
  norm_t2<<<1024, blk, 0, stream>>>(te, Tb, Tck);
  T(CWk, WT1, DD, DD, ckw);
  gemm_bt<EPI_BF16><<<g4(1024, DD), blk, 0, stream>>>(Tck, WT1, Cbk, CK, nullptr,
      48, DD, DD, DD, 1.f, 0, 0, 0, 0, 0);
  T(CWv, WT0, DD, DD, nullptr);
  gemm_bt<EPI_TRANS><<<g4(1024, DD), blk, 0, stream>>>(Tb, WT0, Cbv, Vt, nullptr,
      48, DD, DD, 0, 1.f, 0, 0, 512, 9, (size_t)DD * 512);
  gemm_bt<EPI_BF16S><<<g4(8192, 512), blk, 0, stream>>>(CQ, CK, nullptr, Sc, nullptr,
      48, DD, DD, 512, scl, 12, (size_t)512 * DD, 0, 0, 0);
  softmax_bf16<512><<<8192, blk, 0, stream>>>(Sc);
  gemm8<EPI_BF16><<<g8(8192, DD), blk8, 0, stream>>>(Sc, Vt, nullptr, Cx, nullptr,
      8, 512, 512, DD, 1.f, 12, (size_t)DD * 512, 0, 0, 0);
  T(CWo, WT1, DD, DD, nullptr);
  gemm8<EPI_ACC><<<g8(8192, DD), blk8, 0, stream>>>(Cx, WT1, Cbo, out, nullptr,
      24, DD, DD, DD, 1.f, 0, 0, 0, 0, 0);

  // FFN: LN -> W1(+gelu) in 2 column chunks of 3072 -> W2 acc
  norm_ln<<<8192, blk, 0, stream>>>(x, lnw, lnb, LNo);
  T(W1, WT0, DD, FF, nullptr);
  T(W2, WT1, FF, DD, nullptr);
  for (int c = 0; c < 2; c++) {
    gemm8<EPI_GELU><<<g8(8192, 3072), blk8, 0, stream>>>(LNo, WT0 + (size_t)c * 4718592,
        b1 + c * 3072, H, nullptr, 24, DD, DD, 3072, 1.f, 0, 0, 0, 0, 0);
    gemm8<EPI_ACC><<<g8(8192, DD), blk8, 0, stream>>>(H, WT1 + c * 3072,
        (c == 0) ? b2 : nullptr, out, nullptr, 48, 3072, FF, DD, 1.f, 0, 0, 0, 0, 0);
  }
}